// Round 6
// baseline (342.975 us; speedup 1.0000x reference)
//
#include <hip/hip_runtime.h>
#include <hip/hip_bf16.h>
#include <cstddef>
#include <cstdint>

// Problem constants
#define NB 128
#define NT 4096
#define NC 32
// bits rows: scales {1,16,64,256,1024,4096} -> offsets {0,1,17,81,337,1361}, total 5457
#define BITROWS 5457
#define QV_ROWS 1361          // coarse q rows region in ws (only rows 0..336 used now)
#define QOUT_ELEMS (NB*NT*NC)             // 16777216
#define BITS_ELEMS (NB*BITROWS*NC)        // 22351872

// ws layout (bytes):
//   qv   @ 0          : NB*1361*32 floats (only rows 0..336 written)
//   acc  @ 22298624   : 204 doubles (ent[6], com[6], p[6][32]) = 1632 B
//   S16  @ 22302720   : NB*256*32 floats = 4,194,304 B
#define ACC_OFF  22298624
#define S16_OFF  22302720

__device__ __constant__ float kQSC = 0.17677669529663687f;   // 1/sqrt(32)
__device__ __constant__ float kSIG = 17.67766952966369f;     // 100/sqrt(32)

// exact reference interp: x[lo]*(1-w) + x[hi]*w, no fma contraction
__device__ __forceinline__ float interp_eval(const float* __restrict__ q, int P, int t, int c) {
  float pos = ((float)t + 0.5f) * ((float)P * (1.0f / 4096.0f)) - 0.5f;
  pos = fminf(fmaxf(pos, 0.0f), (float)(P - 1));
  const int lo = (int)pos;
  const int hi = min(lo + 1, P - 1);
  const float w = pos - (float)lo;
  const float a = __fmul_rn(q[lo * NC + c], 1.0f - w);
  const float b = __fmul_rn(q[hi * NC + c], w);
  return __fadd_rn(a, b);
}

// same arithmetic as interp_eval, but q points at an LDS slice whose row 0
// is global coarse row `base` (base may be negative; lo>=0 always so indices fit).
__device__ __forceinline__ float interp_slice(const float* __restrict__ q, int P, int base, int t, int c) {
  float pos = ((float)t + 0.5f) * ((float)P * (1.0f / 4096.0f)) - 0.5f;
  pos = fminf(fmaxf(pos, 0.0f), (float)(P - 1));
  const int lo = (int)pos;
  const int hi = min(lo + 1, P - 1);
  const float w = pos - (float)lo;
  const float a = __fmul_rn(q[(lo - base) * NC + c], 1.0f - w);
  const float b = __fmul_rn(q[(hi - base) * NC + c], w);
  return __fadd_rn(a, b);
}

// per-coarse-element: normalize over C (32 lanes), sign-quantize, write qv/bits, loss elems
// qlsRow / qvG are nullable (compile-time constant null folds the store away).
__device__ __forceinline__ void process_elem(
    float msum, float invn, int b, int rowOff, int j, int c,
    float* qlsRow, float* __restrict__ qvG, float* __restrict__ bitsG,
    float& entA, float& comA, float& pA)
{
  const float m = msum * invn;       // invn is a power of two -> exact
  float ss = m * m;
  #pragma unroll
  for (int mk = 16; mk; mk >>= 1) ss += __shfl_xor(ss, mk, 32);
  const float den = fmaxf(sqrtf(ss), 1e-12f);
  const float fn = m / den;
  const bool bit = fn > 0.0f;
  const float zh = bit ? kQSC : -kQSC;
  const float qvv = fn + (zh - fn);  // reference: quantized = f + (zhat - f)
  if (qlsRow) qlsRow[c] = qvv;
  if (qvG) qvG[(size_t)b * (QV_ROWS * NC) + (size_t)(rowOff + j) * NC + c] = qvv;
  bitsG[(size_t)b * (BITROWS * NC) + (size_t)(rowOff + j) * NC + c] = bit ? 1.0f : 0.0f;
  const float arg = (-4.0f * fn) * kSIG;         // sigmoid(-4*f*100/sqrt(32))
  const float p = 1.0f / (1.0f + __expf(-arg));
  const float ent = -(p * __logf(p + 1e-8f) + (1.0f - p) * __logf((1.0f - p) + 1e-8f));
  const float d = qvv - fn;
  entA += ent; comA += d * d; pA += p;
}

// block-level loss reduction -> double atomics. all threads must call.
__device__ __forceinline__ void reduce_losses(
    int sIdx, float entA, float comA, float pA, int tid, int nWaves,
    double* __restrict__ acc, float* redE, float* redC, float* redP)
{
  float e = entA, cm = comA;
  #pragma unroll
  for (int mk = 32; mk; mk >>= 1) { e += __shfl_xor(e, mk, 64); cm += __shfl_xor(cm, mk, 64); }
  const float p = pA + __shfl_xor(pA, 32, 64);
  const int w = tid >> 6, lane = tid & 63;
  if (lane == 0) { redE[w] = e; redC[w] = cm; }
  if (lane < 32) redP[w * 32 + lane] = p;
  __syncthreads();
  if (tid == 0) {
    double te = 0.0, tc = 0.0;
    for (int i = 0; i < nWaves; ++i) { te += (double)redE[i]; tc += (double)redC[i]; }
    atomicAdd(&acc[sIdx], te);
    atomicAdd(&acc[6 + sIdx], tc);
  }
  if (tid < 32) {
    float tp = 0.0f;
    for (int i = 0; i < nWaves; ++i) tp += redP[i * 32 + tid];
    atomicAdd(&acc[12 + sIdx * 32 + tid], (double)tp);
  }
  __syncthreads();
}

// ---------- P0: granularity-16 sums of f (t-ascending, blocked-sequential) ----------
__global__ __launch_bounds__(256) void k_sum16(const float* __restrict__ f, float* __restrict__ S16) {
  const int idx = blockIdx.x * 256 + threadIdx.x;   // NB*256*32 = 1,048,576
  if (idx >= NB * 256 * NC) return;
  const int c = idx & 31;
  const int j = (idx >> 5) & 255;
  const int b = idx >> 13;
  const float* p = f + (size_t)b * (NT * NC) + (size_t)j * 16 * NC + c;
  float s = 0.0f;
  #pragma unroll
  for (int k = 0; k < 16; ++k) s += p[k * NC];
  S16[idx] = s;
}

// ---------- P1a: scale 0 (pt=1) — deterministic global-T reduction per b ----------
__global__ __launch_bounds__(1024) void k_s0(
    const float* __restrict__ S16g, float* __restrict__ qv,
    float* __restrict__ bitsOut, double* __restrict__ acc)
{
  __shared__ float red[1024];
  __shared__ float redE[16], redC[16], redP[16 * 32];
  const int b = blockIdx.x, tid = threadIdx.x, c = tid & 31;
  const float* __restrict__ sb = S16g + (size_t)b * 8192;
  {
    const int g = tid >> 5;
    float part = 0.0f;
    #pragma unroll
    for (int j = 0; j < 8; ++j) part += sb[(size_t)(g * 8 + j) * NC + c];
    red[tid] = part;
  }
  __syncthreads();
  float entA = 0.0f, comA = 0.0f, pA = 0.0f;
  if (tid < 32) {
    float msum = 0.0f;
    for (int g = 0; g < 32; ++g) msum += red[g * 32 + tid];
    process_elem(msum, 1.0f / 4096.0f, b, 0, 0, tid, nullptr, qv, bitsOut, entA, comA, pA);
  }
  reduce_losses(0, entA, comA, pA, tid, 16, acc, redE, redC, redP);
}

// ---------- P1b: scales 1..3, two blocks per batch element ----------
__global__ __launch_bounds__(1024) void k_coarse2(
    const float* __restrict__ S16g,
    float* __restrict__ qv, float* __restrict__ bitsOut, double* __restrict__ acc)
{
  __shared__ float S[144 * NC];        // rows [start, start+144) (18.4 KB)
  __shared__ float q1s[10 * NC];       // scale-1 rows [8seg-1, 8seg+9)
  __shared__ float q2s[34 * NC];       // scale-2 rows [32seg-1, 32seg+33)
  __shared__ float redE[16], redC[16], redP[16 * 32];
  const int b = blockIdx.x >> 1, seg = blockIdx.x & 1;
  const int tid = threadIdx.x, c = tid & 31;
  const int start = seg * 112;         // seg0: rows [0,144); seg1: rows [112,256)
  const int base1 = 8 * seg - 1, base2 = 32 * seg - 1;
  const float* __restrict__ sb = S16g + (size_t)b * 8192;
  const float* __restrict__ qb = qv + (size_t)b * (QV_ROWS * NC);

  for (int e = tid; e < 144 * NC; e += 1024)
    S[e] = sb[(size_t)(start + (e >> 5)) * NC + (e & 31)];
  __syncthreads();

  // scale-0 subtraction (q0 from k_s0; same float op as original corr pass)
  const float corr = 16.0f * qb[c];
  for (int e = tid; e < 144 * NC; e += 1024) S[e] -= corr;
  __syncthreads();

  float entA, comA, pA;

  // ----- scale 1 (pt=16): 8 own rows + 1 halo row -----
  entA = comA = pA = 0.0f;
  if (tid < 256) {
    const int jl = tid >> 5;
    const int j = 8 * seg + jl;
    float msum = 0.0f;
    for (int jj = 0; jj < 16; ++jj) msum += S[(j * 16 + jj - start) * NC + c];
    process_elem(msum, 1.0f / 256.0f, b, 1, j, c, &q1s[(j - base1) * NC], qv, bitsOut, entA, comA, pA);
  } else if (tid < 288) {
    const int jh = seg ? 7 : 8;        // neighbor's boundary row, recomputed exactly
    float msum = 0.0f;
    for (int jj = 0; jj < 16; ++jj) msum += S[(jh * 16 + jj - start) * NC + c];
    const float m = msum * (1.0f / 256.0f);
    float ss = m * m;
    #pragma unroll
    for (int mk = 16; mk; mk >>= 1) ss += __shfl_xor(ss, mk, 32);
    const float den = fmaxf(sqrtf(ss), 1e-12f);
    const float fn = m / den;
    const float zh = (fn > 0.0f) ? kQSC : -kQSC;
    q1s[(jh - base1) * NC + c] = fn + (zh - fn);
  }
  reduce_losses(1, entA, comA, pA, tid, 16, acc, redE, redC, redP);   // syncs q1s

  // scale-1 correction on own 128 rows + 4-row halo (rows feeding scale-2 halo)
  {
    const int gc0 = seg ? 124 : 0;     // corrected rows [gc0, gc0+132)
    for (int e = tid; e < 132 * NC; e += 1024) {
      const int g = gc0 + (e >> 5);
      float cs = 0.0f;
      #pragma unroll
      for (int k = 0; k < 16; ++k) cs += interp_slice(q1s, 16, base1, g * 16 + k, c);
      S[(g - start) * NC + c] -= cs;
    }
  }
  __syncthreads();

  // ----- scale 2 (pt=64): 32 own rows + 1 halo row -----
  entA = comA = pA = 0.0f;
  {
    const int j2 = 32 * seg + (tid >> 5);
    float msum = 0.0f;
    #pragma unroll
    for (int jj = 0; jj < 4; ++jj) msum += S[(j2 * 4 + jj - start) * NC + c];
    process_elem(msum, 1.0f / 64.0f, b, 17, j2, c, &q2s[(j2 - base2) * NC], qv, bitsOut, entA, comA, pA);
  }
  if (tid < 32) {
    const int j2h = seg ? 31 : 32;     // neighbor's boundary row, recomputed exactly
    float msum = 0.0f;
    #pragma unroll
    for (int jj = 0; jj < 4; ++jj) msum += S[(j2h * 4 + jj - start) * NC + c];
    const float m = msum * (1.0f / 64.0f);
    float ss = m * m;
    #pragma unroll
    for (int mk = 16; mk; mk >>= 1) ss += __shfl_xor(ss, mk, 32);
    const float den = fmaxf(sqrtf(ss), 1e-12f);
    const float fn = m / den;
    const float zh = (fn > 0.0f) ? kQSC : -kQSC;
    q2s[(j2h - base2) * NC + c] = fn + (zh - fn);
  }
  reduce_losses(2, entA, comA, pA, tid, 16, acc, redE, redC, redP);   // syncs q2s

  // scale-2 correction on own 128 rows
  for (int e = tid; e < 128 * NC; e += 1024) {
    const int g = 128 * seg + (e >> 5);
    float cs = 0.0f;
    #pragma unroll
    for (int k = 0; k < 16; ++k) cs += interp_slice(q2s, 64, base2, g * 16 + k, c);
    S[(g - start) * NC + c] -= cs;
  }
  __syncthreads();

  // ----- scale 3 (pt=256): 128 own rows -----
  entA = comA = pA = 0.0f;
  for (int out = tid; out < 128 * NC; out += 1024) {
    const int g = 128 * seg + (out >> 5);
    process_elem(S[(g - start) * NC + c], 1.0f / 16.0f, b, 81, g, c, nullptr, qv, bitsOut, entA, comA, pA);
  }
  reduce_losses(3, entA, comA, pA, tid, 16, acc, redE, redC, redP);
}

// ---------- P2: scales 4+5 fused, 1024 threads/tile, small register carry ----------
// Same 256-t tile as before but 4x the threads: each thread owns 8 t's, so the
// Phase-A partial residual rA and partial q-sum qsA fit in 16 registers
// (rA[2][4], qsA[2][4]) instead of 64 (the R4 failure). Phase B completes the
// exact chains with q4 only: r = rA - q4, qs = qsA + q4. All qout/bits element
// chains bit-identical to the reference; loss partial grouping changes only at
// the double-accumulation level (benign, verified across R3/R5).
__global__ __launch_bounds__(1024) void k_s45(
    const float* __restrict__ f, const float* __restrict__ qv,
    float* __restrict__ qout, float* __restrict__ bitsOut, double* __restrict__ acc)
{
  __shared__ float ql0[NC];            // scale0 (P=1): interp == ql0[c] exactly
  __shared__ float ql1[3 * NC];        // scale1 rows [seg-1, seg+1] clamped
  __shared__ float ql2[6 * NC];        // scale2 rows [4seg-1, 4seg+4] clamped
  __shared__ float ql3[18 * NC];       // scale3 rows [16seg-1, 16seg+16] clamped
  __shared__ float ql4[66 * NC];       // scale4 rows [64seg-1, 64seg+64] (slot 0/65 unused at edges)
  __shared__ float redE[16], redC[16], redP[16 * 32];
  const int b = blockIdx.x >> 4, seg = blockIdx.x & 15;
  const int tid = threadIdx.x, c = tid & 31, rloc = tid >> 5;   // rloc in [0,32)
  const float* __restrict__ qb = qv + (size_t)b * (QV_ROWS * NC);
  const float* __restrict__ fb = f + (size_t)b * (NT * NC);
  const int b1 = seg - 1, b2 = 4 * seg - 1, b3 = 16 * seg - 1, b4 = 64 * seg - 1;
  if (tid < NC) ql0[tid] = qb[tid];
  if (tid < 3 * NC) {
    const int r = min(max(b1 + (tid >> 5), 0), 15);
    ql1[tid] = qb[(1 + r) * NC + (tid & 31)];
  }
  if (tid < 6 * NC) {
    const int r = min(max(b2 + (tid >> 5), 0), 63);
    ql2[tid] = qb[(17 + r) * NC + (tid & 31)];
  }
  if (tid < 18 * NC) {
    const int r = min(max(b3 + (tid >> 5), 0), 255);
    ql3[tid] = qb[(81 + r) * NC + (tid & 31)];
  }
  __syncthreads();

  // register-carried partial residual / partial q-sum for this thread's 8 t's
  float rA[2][4], qsA[2][4];

  // ---- phase A: scale 4 (pt=1024) ----
  float entA = 0.0f, comA = 0.0f, pA = 0.0f;
  #pragma unroll
  for (int pass = 0; pass < 2; ++pass) {
    const int i = seg * 64 + pass * 32 + rloc;            // owned row in [64seg, 64seg+64)
    const float* fp = fb + (size_t)i * 4 * NC + c;
    float msum = 0.0f;
    #pragma unroll
    for (int k = 0; k < 4; ++k) {
      const int t = i * 4 + k;
      const float q0 = ql0[c];                            // exact: P=1 interp == q[c]
      const float q1 = interp_slice(ql1, 16,  b1, t, c);
      const float q2 = interp_slice(ql2, 64,  b2, t, c);
      const float q3 = interp_slice(ql3, 256, b3, t, c);
      float r = fp[k * NC];
      r -= q0; r -= q1; r -= q2; r -= q3;                 // exact reference chain prefix
      float qs = q0; qs += q1; qs += q2; qs += q3;        // exact reference qout prefix
      rA[pass][k] = r;
      qsA[pass][k] = qs;
      msum += r;                                          // sequential t-order
    }
    process_elem(msum, 0.25f, b, 337, i, c,
                 &ql4[(size_t)(i - b4) * NC], nullptr, bitsOut, entA, comA, pA);
  }
  // halo rows: pure compute into LDS, no bits/loss side effects
  {
    int hr = -1;
    if (rloc == 0 && seg > 0)       hr = 64 * seg - 1;    // left halo
    else if (rloc == 1 && seg < 15) hr = 64 * seg + 64;   // right halo
    if (hr >= 0) {
      const float* fp = fb + (size_t)hr * 4 * NC + c;
      float msum = 0.0f;
      #pragma unroll
      for (int k = 0; k < 4; ++k) {
        const int t = hr * 4 + k;
        float r = fp[k * NC];
        r -= ql0[c];
        r -= interp_slice(ql1, 16,  b1, t, c);
        r -= interp_slice(ql2, 64,  b2, t, c);
        r -= interp_slice(ql3, 256, b3, t, c);
        msum += r;
      }
      const float m = msum * 0.25f;
      float ss = m * m;
      #pragma unroll
      for (int mk = 16; mk; mk >>= 1) ss += __shfl_xor(ss, mk, 32);
      const float den = fmaxf(sqrtf(ss), 1e-12f);
      const float fn = m / den;
      const float zh = (fn > 0.0f) ? kQSC : -kQSC;
      ql4[(size_t)(hr - b4) * NC + c] = fn + (zh - fn);
    }
  }
  reduce_losses(4, entA, comA, pA, tid, 16, acc, redE, redC, redP);  // also syncs ql4

  // ---- phase B: scale 5 (pt=T), qout + bits + losses ----
  entA = 0.0f; comA = 0.0f; pA = 0.0f;
  #pragma unroll
  for (int pass = 0; pass < 2; ++pass) {
    const int i = seg * 64 + pass * 32 + rloc;
    #pragma unroll
    for (int k = 0; k < 4; ++k) {
      const int t = i * 4 + k;
      const float q4 = interp_slice(ql4, 1024, b4, t, c);
      float r = rA[pass][k];
      r -= q4;                                            // completes exact chain: fv-q0-q1-q2-q3-q4
      float qs = qsA[pass][k];
      qs += q4;                                           // completes exact qout sum order
      float ss = r * r;
      #pragma unroll
      for (int mk = 16; mk; mk >>= 1) ss += __shfl_xor(ss, mk, 32);
      const float den = fmaxf(sqrtf(ss), 1e-12f);
      const float fn = r / den;
      const bool bit = fn > 0.0f;
      const float zh = bit ? kQSC : -kQSC;
      const float qvv = fn + (zh - fn);
      qout[(size_t)b * (NT * NC) + (size_t)t * NC + c] = qs + qvv;
      bitsOut[(size_t)b * (BITROWS * NC) + (size_t)(1361 + t) * NC + c] = bit ? 1.0f : 0.0f;
      const float arg = (-4.0f * fn) * kSIG;
      const float p = 1.0f / (1.0f + __expf(-arg));
      entA += -(p * __logf(p + 1e-8f) + (1.0f - p) * __logf((1.0f - p) + 1e-8f));
      const float d = qvv - fn;
      comA += d * d;
      pA += p;
    }
  }
  reduce_losses(5, entA, comA, pA, tid, 16, acc, redE, redC, redP);
}

// ---------- P4: finalize 6 scalar losses ----------
__global__ void k_losses(const double* __restrict__ acc, float* __restrict__ out) {
  const int s = threadIdx.x;
  if (s >= 6) return;
  const int pts[6] = {1, 16, 64, 256, 1024, 4096};
  const double n = 128.0 * (double)pts[s];
  const double pse = acc[s] / n;
  const double commit = acc[6 + s] / n;
  double cbe = 0.0;
  for (int c = 0; c < 32; ++c) {
    const double ap = acc[12 + s * 32 + c] / n;
    cbe += -(ap * log(ap + 1e-8) + (1.0 - ap) * log((1.0 - ap) + 1e-8));
  }
  const double pen = (pse - cbe) / 100.0;
  out[s] = (float)(pen * 0.1 + commit * 0.2);
}

extern "C" void kernel_launch(void* const* d_in, const int* in_sizes, int n_in,
                              void* d_out, int out_size, void* d_ws, size_t ws_size,
                              hipStream_t stream) {
  const float* f = (const float*)d_in[0];
  float* qout = (float*)d_out;
  float* bitsOut = qout + QOUT_ELEMS;
  float* lossesOut = qout + (QOUT_ELEMS + BITS_ELEMS);
  float* qv = (float*)d_ws;
  double* acc = (double*)((char*)d_ws + ACC_OFF);
  float* S16 = (float*)((char*)d_ws + S16_OFF);

  hipMemsetAsync(acc, 0, 204 * sizeof(double), stream);
  k_sum16<<<4096, 256, 0, stream>>>(f, S16);
  k_s0<<<NB, 1024, 0, stream>>>(S16, qv, bitsOut, acc);
  k_coarse2<<<NB * 2, 1024, 0, stream>>>(S16, qv, bitsOut, acc);
  k_s45<<<NB * 16, 1024, 0, stream>>>(f, qv, qout, bitsOut, acc);
  k_losses<<<1, 64, 0, stream>>>(acc, lossesOut);
}

// Round 7
// 320.644 us; speedup vs baseline: 1.0696x; 1.0696x over previous
//
#include <hip/hip_runtime.h>
#include <hip/hip_bf16.h>
#include <cstddef>
#include <cstdint>

// Problem constants
#define NB 128
#define NT 4096
#define NC 32
// bits rows: scales {1,16,64,256,1024,4096} -> offsets {0,1,17,81,337,1361}, total 5457
#define BITROWS 5457
#define QV_ROWS 1361          // coarse q rows region in ws (only rows 0..336 used now)
#define QOUT_ELEMS (NB*NT*NC)             // 16777216
#define BITS_ELEMS (NB*BITROWS*NC)        // 22351872

// ws layout (bytes):
//   qv   @ 0          : NB*1361*32 floats (only rows 0..336 written)
//   acc  @ 22298624   : 204 doubles (ent[6], com[6], p[6][32]) = 1632 B
//   S16  @ 22302720   : NB*256*32 floats = 4,194,304 B
#define ACC_OFF  22298624
#define S16_OFF  22302720

__device__ __constant__ float kQSC = 0.17677669529663687f;   // 1/sqrt(32)
__device__ __constant__ float kSIG = 17.67766952966369f;     // 100/sqrt(32)

// exact reference interp: x[lo]*(1-w) + x[hi]*w, no fma contraction
__device__ __forceinline__ float interp_eval(const float* __restrict__ q, int P, int t, int c) {
  float pos = ((float)t + 0.5f) * ((float)P * (1.0f / 4096.0f)) - 0.5f;
  pos = fminf(fmaxf(pos, 0.0f), (float)(P - 1));
  const int lo = (int)pos;
  const int hi = min(lo + 1, P - 1);
  const float w = pos - (float)lo;
  const float a = __fmul_rn(q[lo * NC + c], 1.0f - w);
  const float b = __fmul_rn(q[hi * NC + c], w);
  return __fadd_rn(a, b);
}

// same arithmetic as interp_eval, but q points at an LDS slice whose row 0
// is global coarse row `base` (base may be negative; lo>=0 always so indices fit).
__device__ __forceinline__ float interp_slice(const float* __restrict__ q, int P, int base, int t, int c) {
  float pos = ((float)t + 0.5f) * ((float)P * (1.0f / 4096.0f)) - 0.5f;
  pos = fminf(fmaxf(pos, 0.0f), (float)(P - 1));
  const int lo = (int)pos;
  const int hi = min(lo + 1, P - 1);
  const float w = pos - (float)lo;
  const float a = __fmul_rn(q[(lo - base) * NC + c], 1.0f - w);
  const float b = __fmul_rn(q[(hi - base) * NC + c], w);
  return __fadd_rn(a, b);
}

// per-coarse-element: normalize over C (32 lanes), sign-quantize, write qv/bits, loss elems
// qlsRow / qvG are nullable (compile-time constant null folds the store away).
__device__ __forceinline__ void process_elem(
    float msum, float invn, int b, int rowOff, int j, int c,
    float* qlsRow, float* __restrict__ qvG, float* __restrict__ bitsG,
    float& entA, float& comA, float& pA)
{
  const float m = msum * invn;       // invn is a power of two -> exact
  float ss = m * m;
  #pragma unroll
  for (int mk = 16; mk; mk >>= 1) ss += __shfl_xor(ss, mk, 32);
  const float den = fmaxf(sqrtf(ss), 1e-12f);
  const float fn = m / den;
  const bool bit = fn > 0.0f;
  const float zh = bit ? kQSC : -kQSC;
  const float qvv = fn + (zh - fn);  // reference: quantized = f + (zhat - f)
  if (qlsRow) qlsRow[c] = qvv;
  if (qvG) qvG[(size_t)b * (QV_ROWS * NC) + (size_t)(rowOff + j) * NC + c] = qvv;
  bitsG[(size_t)b * (BITROWS * NC) + (size_t)(rowOff + j) * NC + c] = bit ? 1.0f : 0.0f;
  const float arg = (-4.0f * fn) * kSIG;         // sigmoid(-4*f*100/sqrt(32))
  const float p = 1.0f / (1.0f + __expf(-arg));
  const float ent = -(p * __logf(p + 1e-8f) + (1.0f - p) * __logf((1.0f - p) + 1e-8f));
  const float d = qvv - fn;
  entA += ent; comA += d * d; pA += p;
}

// block-level loss reduction -> double atomics. all threads must call.
__device__ __forceinline__ void reduce_losses(
    int sIdx, float entA, float comA, float pA, int tid, int nWaves,
    double* __restrict__ acc, float* redE, float* redC, float* redP)
{
  float e = entA, cm = comA;
  #pragma unroll
  for (int mk = 32; mk; mk >>= 1) { e += __shfl_xor(e, mk, 64); cm += __shfl_xor(cm, mk, 64); }
  const float p = pA + __shfl_xor(pA, 32, 64);
  const int w = tid >> 6, lane = tid & 63;
  if (lane == 0) { redE[w] = e; redC[w] = cm; }
  if (lane < 32) redP[w * 32 + lane] = p;
  __syncthreads();
  if (tid == 0) {
    double te = 0.0, tc = 0.0;
    for (int i = 0; i < nWaves; ++i) { te += (double)redE[i]; tc += (double)redC[i]; }
    atomicAdd(&acc[sIdx], te);
    atomicAdd(&acc[6 + sIdx], tc);
  }
  if (tid < 32) {
    float tp = 0.0f;
    for (int i = 0; i < nWaves; ++i) tp += redP[i * 32 + tid];
    atomicAdd(&acc[12 + sIdx * 32 + tid], (double)tp);
  }
  __syncthreads();
}

// ---------- P0: granularity-16 sums of f (t-ascending, blocked-sequential) ----------
__global__ __launch_bounds__(256) void k_sum16(const float* __restrict__ f, float* __restrict__ S16) {
  const int idx = blockIdx.x * 256 + threadIdx.x;   // NB*256*32 = 1,048,576
  if (idx >= NB * 256 * NC) return;
  const int c = idx & 31;
  const int j = (idx >> 5) & 255;
  const int b = idx >> 13;
  const float* p = f + (size_t)b * (NT * NC) + (size_t)j * 16 * NC + c;
  float s = 0.0f;
  #pragma unroll
  for (int k = 0; k < 16; ++k) s += p[k * NC];
  S16[idx] = s;
}

// ---------- P1a: scale 0 (pt=1) — deterministic global-T reduction per b ----------
__global__ __launch_bounds__(1024) void k_s0(
    const float* __restrict__ S16g, float* __restrict__ qv,
    float* __restrict__ bitsOut, double* __restrict__ acc)
{
  __shared__ float red[1024];
  __shared__ float redE[16], redC[16], redP[16 * 32];
  const int b = blockIdx.x, tid = threadIdx.x, c = tid & 31;
  const float* __restrict__ sb = S16g + (size_t)b * 8192;
  {
    const int g = tid >> 5;
    float part = 0.0f;
    #pragma unroll
    for (int j = 0; j < 8; ++j) part += sb[(size_t)(g * 8 + j) * NC + c];
    red[tid] = part;
  }
  __syncthreads();
  float entA = 0.0f, comA = 0.0f, pA = 0.0f;
  if (tid < 32) {
    float msum = 0.0f;
    for (int g = 0; g < 32; ++g) msum += red[g * 32 + tid];
    process_elem(msum, 1.0f / 4096.0f, b, 0, 0, tid, nullptr, qv, bitsOut, entA, comA, pA);
  }
  reduce_losses(0, entA, comA, pA, tid, 16, acc, redE, redC, redP);
}

// ---------- P1b: scales 1..3, two blocks per batch element ----------
__global__ __launch_bounds__(1024) void k_coarse2(
    const float* __restrict__ S16g,
    float* __restrict__ qv, float* __restrict__ bitsOut, double* __restrict__ acc)
{
  __shared__ float S[144 * NC];        // rows [start, start+144) (18.4 KB)
  __shared__ float q1s[10 * NC];       // scale-1 rows [8seg-1, 8seg+9)
  __shared__ float q2s[34 * NC];       // scale-2 rows [32seg-1, 32seg+33)
  __shared__ float redE[16], redC[16], redP[16 * 32];
  const int b = blockIdx.x >> 1, seg = blockIdx.x & 1;
  const int tid = threadIdx.x, c = tid & 31;
  const int start = seg * 112;         // seg0: rows [0,144); seg1: rows [112,256)
  const int base1 = 8 * seg - 1, base2 = 32 * seg - 1;
  const float* __restrict__ sb = S16g + (size_t)b * 8192;
  const float* __restrict__ qb = qv + (size_t)b * (QV_ROWS * NC);

  for (int e = tid; e < 144 * NC; e += 1024)
    S[e] = sb[(size_t)(start + (e >> 5)) * NC + (e & 31)];
  __syncthreads();

  // scale-0 subtraction (q0 from k_s0; same float op as original corr pass)
  const float corr = 16.0f * qb[c];
  for (int e = tid; e < 144 * NC; e += 1024) S[e] -= corr;
  __syncthreads();

  float entA, comA, pA;

  // ----- scale 1 (pt=16): 8 own rows + 1 halo row -----
  entA = comA = pA = 0.0f;
  if (tid < 256) {
    const int jl = tid >> 5;
    const int j = 8 * seg + jl;
    float msum = 0.0f;
    for (int jj = 0; jj < 16; ++jj) msum += S[(j * 16 + jj - start) * NC + c];
    process_elem(msum, 1.0f / 256.0f, b, 1, j, c, &q1s[(j - base1) * NC], qv, bitsOut, entA, comA, pA);
  } else if (tid < 288) {
    const int jh = seg ? 7 : 8;        // neighbor's boundary row, recomputed exactly
    float msum = 0.0f;
    for (int jj = 0; jj < 16; ++jj) msum += S[(jh * 16 + jj - start) * NC + c];
    const float m = msum * (1.0f / 256.0f);
    float ss = m * m;
    #pragma unroll
    for (int mk = 16; mk; mk >>= 1) ss += __shfl_xor(ss, mk, 32);
    const float den = fmaxf(sqrtf(ss), 1e-12f);
    const float fn = m / den;
    const float zh = (fn > 0.0f) ? kQSC : -kQSC;
    q1s[(jh - base1) * NC + c] = fn + (zh - fn);
  }
  reduce_losses(1, entA, comA, pA, tid, 16, acc, redE, redC, redP);   // syncs q1s

  // scale-1 correction on own 128 rows + 4-row halo (rows feeding scale-2 halo)
  {
    const int gc0 = seg ? 124 : 0;     // corrected rows [gc0, gc0+132)
    for (int e = tid; e < 132 * NC; e += 1024) {
      const int g = gc0 + (e >> 5);
      float cs = 0.0f;
      #pragma unroll
      for (int k = 0; k < 16; ++k) cs += interp_slice(q1s, 16, base1, g * 16 + k, c);
      S[(g - start) * NC + c] -= cs;
    }
  }
  __syncthreads();

  // ----- scale 2 (pt=64): 32 own rows + 1 halo row -----
  entA = comA = pA = 0.0f;
  {
    const int j2 = 32 * seg + (tid >> 5);
    float msum = 0.0f;
    #pragma unroll
    for (int jj = 0; jj < 4; ++jj) msum += S[(j2 * 4 + jj - start) * NC + c];
    process_elem(msum, 1.0f / 64.0f, b, 17, j2, c, &q2s[(j2 - base2) * NC], qv, bitsOut, entA, comA, pA);
  }
  if (tid < 32) {
    const int j2h = seg ? 31 : 32;     // neighbor's boundary row, recomputed exactly
    float msum = 0.0f;
    #pragma unroll
    for (int jj = 0; jj < 4; ++jj) msum += S[(j2h * 4 + jj - start) * NC + c];
    const float m = msum * (1.0f / 64.0f);
    float ss = m * m;
    #pragma unroll
    for (int mk = 16; mk; mk >>= 1) ss += __shfl_xor(ss, mk, 32);
    const float den = fmaxf(sqrtf(ss), 1e-12f);
    const float fn = m / den;
    const float zh = (fn > 0.0f) ? kQSC : -kQSC;
    q2s[(j2h - base2) * NC + c] = fn + (zh - fn);
  }
  reduce_losses(2, entA, comA, pA, tid, 16, acc, redE, redC, redP);   // syncs q2s

  // scale-2 correction on own 128 rows
  for (int e = tid; e < 128 * NC; e += 1024) {
    const int g = 128 * seg + (e >> 5);
    float cs = 0.0f;
    #pragma unroll
    for (int k = 0; k < 16; ++k) cs += interp_slice(q2s, 64, base2, g * 16 + k, c);
    S[(g - start) * NC + c] -= cs;
  }
  __syncthreads();

  // ----- scale 3 (pt=256): 128 own rows -----
  entA = comA = pA = 0.0f;
  for (int out = tid; out < 128 * NC; out += 1024) {
    const int g = 128 * seg + (out >> 5);
    process_elem(S[(g - start) * NC + c], 1.0f / 16.0f, b, 81, g, c, nullptr, qv, bitsOut, entA, comA, pA);
  }
  reduce_losses(3, entA, comA, pA, tid, 16, acc, redE, redC, redP);
}

// ---------- P2: scales 4+5 fused, 256 threads, 1-pass software pipeline ----------
// A(p) computes scale-4 row p (per thread) + keeps rA/qsA (chain prefixes) for
// ONE pass only; after a barrier, B(p-1) completes the exact chains with q4
// (ql4 rows p-1..p are ready). Carry = 16 VGPRs; ILP = 8 passes (the R4/R6
// failure modes — VGPR blowup / barrier granularity — are both avoided).
// All qout/bits chains bit-identical to reference; loss grouping changes only
// at the double-accumulation level (benign, verified R3/R5).
__global__ __launch_bounds__(256) void k_s45(
    const float* __restrict__ f, const float* __restrict__ qv,
    float* __restrict__ qout, float* __restrict__ bitsOut, double* __restrict__ acc)
{
  __shared__ float ql0[NC];            // scale0 (P=1): interp == ql0[c] exactly
  __shared__ float ql1[3 * NC];        // scale1 rows [seg-1, seg+1] clamped
  __shared__ float ql2[6 * NC];        // scale2 rows [4seg-1, 4seg+4] clamped
  __shared__ float ql3[18 * NC];       // scale3 rows [16seg-1, 16seg+16] clamped
  __shared__ float ql4[66 * NC];       // scale4 rows [64seg-1, 64seg+64] (slot 0/65 unused at edges)
  __shared__ float redE[4], redC[4], redP[4 * 32];
  const int b = blockIdx.x >> 4, seg = blockIdx.x & 15;
  const int tid = threadIdx.x, c = tid & 31, rloc = tid >> 5;   // rloc in [0,8)
  const float* __restrict__ qb = qv + (size_t)b * (QV_ROWS * NC);
  const float* __restrict__ fb = f + (size_t)b * (NT * NC);
  const int b1 = seg - 1, b2 = 4 * seg - 1, b3 = 16 * seg - 1, b4 = 64 * seg - 1;
  if (tid < NC) ql0[tid] = qb[tid];
  for (int e = tid; e < 3 * NC; e += 256) {
    const int r = min(max(b1 + (e >> 5), 0), 15);
    ql1[e] = qb[(1 + r) * NC + (e & 31)];
  }
  for (int e = tid; e < 6 * NC; e += 256) {
    const int r = min(max(b2 + (e >> 5), 0), 63);
    ql2[e] = qb[(17 + r) * NC + (e & 31)];
  }
  for (int e = tid; e < 18 * NC; e += 256) {
    const int r = min(max(b3 + (e >> 5), 0), 255);
    ql3[e] = qb[(81 + r) * NC + (e & 31)];
  }
  __syncthreads();

  float entA4 = 0.0f, comA4 = 0.0f, pA4 = 0.0f;   // scale-4 losses
  float entB = 0.0f, comB = 0.0f, pB = 0.0f;      // scale-5 losses

  // Phase-A body: scale-4 row for pass p; fills rc/qc (chain prefixes)
  auto do_A = [&](int p, float rc[4], float qc[4]) {
    const int i = seg * 64 + p * 8 + rloc;
    const float* fp = fb + (size_t)i * 4 * NC + c;
    float msum = 0.0f;
    #pragma unroll
    for (int k = 0; k < 4; ++k) {
      const int t = i * 4 + k;
      const float q0 = ql0[c];                            // exact: P=1 interp == q[c]
      const float q1 = interp_slice(ql1, 16,  b1, t, c);
      const float q2 = interp_slice(ql2, 64,  b2, t, c);
      const float q3 = interp_slice(ql3, 256, b3, t, c);
      float r = fp[k * NC];
      r -= q0; r -= q1; r -= q2; r -= q3;                 // exact reference chain prefix
      float qs = q0; qs += q1; qs += q2; qs += q3;        // exact reference qout prefix
      rc[k] = r; qc[k] = qs;
      msum += r;                                          // sequential t-order
    }
    process_elem(msum, 0.25f, b, 337, i, c,
                 &ql4[(size_t)(i - b4) * NC], nullptr, bitsOut, entA4, comA4, pA4);
  };

  // halo row: pure compute into LDS, no bits/loss side effects
  auto do_halo = [&](int hr) {
    const float* fp = fb + (size_t)hr * 4 * NC + c;
    float msum = 0.0f;
    #pragma unroll
    for (int k = 0; k < 4; ++k) {
      const int t = hr * 4 + k;
      float r = fp[k * NC];
      r -= ql0[c];
      r -= interp_slice(ql1, 16,  b1, t, c);
      r -= interp_slice(ql2, 64,  b2, t, c);
      r -= interp_slice(ql3, 256, b3, t, c);
      msum += r;
    }
    const float m = msum * 0.25f;
    float ss = m * m;
    #pragma unroll
    for (int mk = 16; mk; mk >>= 1) ss += __shfl_xor(ss, mk, 32);
    const float den = fmaxf(sqrtf(ss), 1e-12f);
    const float fn = m / den;
    const float zh = (fn > 0.0f) ? kQSC : -kQSC;
    ql4[(size_t)(hr - b4) * NC + c] = fn + (zh - fn);
  };

  // Phase-B body: scale-5 for pass p using carried prefixes
  auto do_B = [&](int p, const float rc[4], const float qc[4]) {
    const int i = seg * 64 + p * 8 + rloc;
    #pragma unroll
    for (int k = 0; k < 4; ++k) {
      const int t = i * 4 + k;
      const float q4 = interp_slice(ql4, 1024, b4, t, c);
      float r = rc[k];
      r -= q4;                                            // completes exact chain: fv-q0..-q4
      float qs = qc[k];
      qs += q4;                                           // completes exact qout sum order
      float ss = r * r;
      #pragma unroll
      for (int mk = 16; mk; mk >>= 1) ss += __shfl_xor(ss, mk, 32);
      const float den = fmaxf(sqrtf(ss), 1e-12f);
      const float fn = r / den;
      const bool bit = fn > 0.0f;
      const float zh = bit ? kQSC : -kQSC;
      const float qvv = fn + (zh - fn);
      qout[(size_t)b * (NT * NC) + (size_t)t * NC + c] = qs + qvv;
      bitsOut[(size_t)b * (BITROWS * NC) + (size_t)(1361 + t) * NC + c] = bit ? 1.0f : 0.0f;
      const float arg = (-4.0f * fn) * kSIG;
      const float p2 = 1.0f / (1.0f + __expf(-arg));
      entB += -(p2 * __logf(p2 + 1e-8f) + (1.0f - p2) * __logf((1.0f - p2) + 1e-8f));
      const float d = qvv - fn;
      comB += d * d;
      pB += p2;
    }
  };

  float rAp[4], qsAp[4];           // prev-pass carry
  float rAc[4], qsAc[4];           // current-pass carry

  do_A(0, rAp, qsAp);
  if (rloc == 0 && seg > 0) do_halo(64 * seg - 1);        // left halo (with pass 0)

  for (int p = 1; p < 8; ++p) {
    do_A(p, rAc, qsAc);
    __syncthreads();               // ql4 rows of pass p (and p-1) visible
    do_B(p - 1, rAp, qsAp);
    #pragma unroll
    for (int k = 0; k < 4; ++k) { rAp[k] = rAc[k]; qsAp[k] = qsAc[k]; }
  }
  if (rloc == 1 && seg < 15) do_halo(64 * seg + 64);      // right halo (before last B)
  __syncthreads();
  do_B(7, rAp, qsAp);

  reduce_losses(4, entA4, comA4, pA4, tid, 4, acc, redE, redC, redP);
  reduce_losses(5, entB, comB, pB, tid, 4, acc, redE, redC, redP);
}

// ---------- P4: finalize 6 scalar losses ----------
__global__ void k_losses(const double* __restrict__ acc, float* __restrict__ out) {
  const int s = threadIdx.x;
  if (s >= 6) return;
  const int pts[6] = {1, 16, 64, 256, 1024, 4096};
  const double n = 128.0 * (double)pts[s];
  const double pse = acc[s] / n;
  const double commit = acc[6 + s] / n;
  double cbe = 0.0;
  for (int c = 0; c < 32; ++c) {
    const double ap = acc[12 + s * 32 + c] / n;
    cbe += -(ap * log(ap + 1e-8) + (1.0 - ap) * log((1.0 - ap) + 1e-8));
  }
  const double pen = (pse - cbe) / 100.0;
  out[s] = (float)(pen * 0.1 + commit * 0.2);
}

extern "C" void kernel_launch(void* const* d_in, const int* in_sizes, int n_in,
                              void* d_out, int out_size, void* d_ws, size_t ws_size,
                              hipStream_t stream) {
  const float* f = (const float*)d_in[0];
  float* qout = (float*)d_out;
  float* bitsOut = qout + QOUT_ELEMS;
  float* lossesOut = qout + (QOUT_ELEMS + BITS_ELEMS);
  float* qv = (float*)d_ws;
  double* acc = (double*)((char*)d_ws + ACC_OFF);
  float* S16 = (float*)((char*)d_ws + S16_OFF);

  hipMemsetAsync(acc, 0, 204 * sizeof(double), stream);
  k_sum16<<<4096, 256, 0, stream>>>(f, S16);
  k_s0<<<NB, 1024, 0, stream>>>(S16, qv, bitsOut, acc);
  k_coarse2<<<NB * 2, 1024, 0, stream>>>(S16, qv, bitsOut, acc);
  k_s45<<<NB * 16, 256, 0, stream>>>(f, qv, qout, bitsOut, acc);
  k_losses<<<1, 64, 0, stream>>>(acc, lossesOut);
}